// Round 1
// baseline (212.165 us; speedup 1.0000x reference)
//
#include <hip/hip_runtime.h>
#include <math.h>

// ws layout (float offsets)
#define PA_OFF    0        // 784   patch_grad partial sums [196 patches][4 chunks]
#define APOOL_OFF 1024     // 588   attack_w mean-pool (unmasked), k = c*196 + px*14 + py
#define MA_OFF    2048     // 588   masked attack pool
#define IPOOL_OFF 4096     // 75264 input mean-pool [128 b][588 k]
#define PL_OFF    81920    // 524288 logits partials [4 ksplit][128 b][1024 n]

// ---------------------------------------------------------------------------
// K1: fused big-memory kernel.
//   blocks [0,384):    input mean-pool, one (b,c) image per block (200 KB)
//   blocks [384,1168): patch_grad partial reduce, (patch p, 32-batch chunk) (96 KB)
//   blocks [1168,1210): attack_w mean-pool, one (c,px) strip per block
__global__ __launch_bounds__(256) void k1_fused(
    const float* __restrict__ inputs,
    const float* __restrict__ patch_grad,
    const float* __restrict__ attack_w,
    float* __restrict__ ws)
{
  __shared__ __align__(16) float lds[3136];
  const int bid = blockIdx.x;
  const int t   = threadIdx.x;

  if (bid < 384) {
    // ---- input mean-pool: b = bid/3, c = bid%3 ----
    const int b = bid / 3, c = bid - b * 3;
    const float* img = inputs + (size_t)bid * 50176;  // (b*3+c)*224*224
    if (t < 224) {
      const int c4 = t % 56, rg = t / 56;   // column float4-group, row-group
      for (int px = 0; px < 14; ++px) {
        float s = 0.f;
        #pragma unroll
        for (int jj = 0; jj < 4; ++jj) {
          const int row = px * 16 + jj * 4 + rg;
          const float4 v = *(const float4*)(img + row * 224 + c4 * 4);
          s += v.x + v.y + v.z + v.w;
        }
        lds[(px * 4 + rg) * 56 + c4] = s;
      }
    }
    __syncthreads();
    if (t < 196) {
      const int px = t / 14, py = t - px * 14;
      float s = 0.f;
      #pragma unroll
      for (int rg = 0; rg < 4; ++rg)
        #pragma unroll
        for (int i4 = 0; i4 < 4; ++i4)
          s += lds[(px * 4 + rg) * 56 + py * 4 + i4];
      ws[IPOOL_OFF + (size_t)b * 588 + c * 196 + t] = s * (1.f / 256.f);
    }
  } else if (bid < 1168) {
    // ---- patch_grad partial reduce ----
    const int a = bid - 384;
    const int p = a >> 2, chunk = a & 3;          // patch, 32-batch chunk
    const float* base = patch_grad + (size_t)chunk * 32 * 150528 + (size_t)p * 768;
    float ax = 0, ay = 0, az = 0, aw = 0;
    #pragma unroll
    for (int j = 0; j < 24; ++j) {
      const int idx = j * 256 + t;          // float4 index in [0,6144)
      const int r   = idx / 192;            // batch row within chunk
      const int off = idx - r * 192;        // float4 offset within 768-row
      const float4 v = *(const float4*)(base + (size_t)r * 150528 + off * 4);
      ax += v.x; ay += v.y; az += v.z; aw += v.w;
    }
    float acc = (ax + ay) + (az + aw);
    #pragma unroll
    for (int o = 32; o > 0; o >>= 1) acc += __shfl_down(acc, o, 64);
    if ((t & 63) == 0) lds[t >> 6] = acc;
    __syncthreads();
    if (t == 0) ws[PA_OFF + a] = lds[0] + lds[1] + lds[2] + lds[3];
  } else {
    // ---- attack_w mean-pool: one (c, px) strip ----
    const int a = bid - 1168;                 // 0..41
    const int c = a / 14, px = a - c * 14;
    const float* img = attack_w + (size_t)c * 50176;
    if (t < 224) {
      const int c4 = t % 56, rg = t / 56;
      float s = 0.f;
      #pragma unroll
      for (int jj = 0; jj < 4; ++jj) {
        const int row = px * 16 + jj * 4 + rg;
        const float4 v = *(const float4*)(img + row * 224 + c4 * 4);
        s += v.x + v.y + v.z + v.w;
      }
      lds[rg * 56 + c4] = s;
    }
    __syncthreads();
    if (t < 14) {
      float s = 0.f;
      #pragma unroll
      for (int rg = 0; rg < 4; ++rg)
        for (int i4 = 0; i4 < 4; ++i4)
          s += lds[rg * 56 + t * 4 + i4];
      ws[APOOL_OFF + c * 196 + px * 14 + t] = s * (1.f / 256.f);
    }
  }
}

// ---------------------------------------------------------------------------
// K2: finish sum_patch, top-20 selection by rank, masked attack pool; zero loss.
__global__ __launch_bounds__(256) void k2_topk(float* __restrict__ ws,
                                               float* __restrict__ d_loss)
{
  __shared__ float sp[196];
  __shared__ float maskp[196];
  const int t = threadIdx.x;
  if (t < 196) {
    const float* pa = ws + PA_OFF;
    float s = 0.f;
    #pragma unroll
    for (int j = 0; j < 4; ++j) s += pa[t * 4 + j];
    sp[t] = s;
  }
  if (t == 0) *d_loss = 0.f;
  __syncthreads();
  if (t < 196) {
    const float v = sp[t];
    int cnt = 0;
    for (int j = 0; j < 196; ++j) {
      const float u = sp[j];
      cnt += (u > v || (u == v && j < t)) ? 1 : 0;   // rank with index tie-break
    }
    maskp[t] = (cnt < 20) ? 1.f : 0.f;
  }
  __syncthreads();
  for (int k = t; k < 588; k += 256) {
    const int p = k % 196;
    ws[MA_OFF + k] = maskp[p] * ws[APOOL_OFF + k];
  }
}

// ---------------------------------------------------------------------------
// K3: logits = (ipool + ma) @ w_cls, split-K=4 into partials.
// bid = (bg*16 + nt)*4 + ks : bg in [0,8) (16 b's), nt in [0,16) (64 n's), ks in [0,4)
__global__ __launch_bounds__(256) void k3_gemm(const float* __restrict__ w_cls,
                                               float* __restrict__ ws)
{
  __shared__ __align__(16) float lp[147 * 16];
  const int bid = blockIdx.x;
  const int ks = bid & 3;
  const int nt = (bid >> 2) & 15;
  const int bg = bid >> 6;
  const int t  = threadIdx.x;
  const float* ipool = ws + IPOOL_OFF;
  const float* ma    = ws + MA_OFF;
  for (int idx = t; idx < 2352; idx += 256) {
    const int bb = idx / 147;
    const int kk = idx - bb * 147;
    const int k  = ks * 147 + kk;
    lp[kk * 16 + bb] = ipool[(size_t)(bg * 16 + bb) * 588 + k] + ma[k];
  }
  __syncthreads();
  const int lane = t & 63, g = t >> 6;
  const int n = nt * 64 + lane;
  const bool valid = n < 1000;
  float a0 = 0, a1 = 0, a2 = 0, a3 = 0;
  const float* wc = w_cls + (size_t)ks * 147 * 1000 + n;
  #pragma unroll 7
  for (int kk = 0; kk < 147; ++kk) {
    const float w = valid ? wc[(size_t)kk * 1000] : 0.f;
    const float4 pv = *(const float4*)&lp[kk * 16 + g * 4];  // wave-uniform -> broadcast
    a0 += pv.x * w; a1 += pv.y * w; a2 += pv.z * w; a3 += pv.w * w;
  }
  float* pl = ws + PL_OFF;
  const int rowb = ks * 128 + bg * 16 + g * 4;
  pl[(size_t)(rowb + 0) * 1024 + n] = a0;
  pl[(size_t)(rowb + 1) * 1024 + n] = a1;
  pl[(size_t)(rowb + 2) * 1024 + n] = a2;
  pl[(size_t)(rowb + 3) * 1024 + n] = a3;
}

// ---------------------------------------------------------------------------
// K4: per-b softmax -> prob (output 0); log_softmax(prob) -> ce -> loss atomic.
__global__ __launch_bounds__(256) void k4_softmax(const float* __restrict__ ws,
                                                  const int* __restrict__ targets,
                                                  float* __restrict__ out)
{
  __shared__ float red[4];
  __shared__ float sh_pt;
  const int b = blockIdx.x, t = threadIdx.x;
  const float* pl = ws + PL_OFF;
  float l[4]; bool val[4];
  #pragma unroll
  for (int j = 0; j < 4; ++j) {
    const int n = j * 256 + t;
    val[j] = (n < 1000);
    float s = -INFINITY;
    if (val[j]) {
      s = 0.f;
      #pragma unroll
      for (int ks = 0; ks < 4; ++ks) s += pl[(size_t)(ks * 128 + b) * 1024 + n];
    }
    l[j] = s;
  }
  // block max of logits
  float m = fmaxf(fmaxf(l[0], l[1]), fmaxf(l[2], l[3]));
  #pragma unroll
  for (int o = 32; o > 0; o >>= 1) m = fmaxf(m, __shfl_down(m, o, 64));
  if ((t & 63) == 0) red[t >> 6] = m;
  __syncthreads();
  const float m1 = fmaxf(fmaxf(red[0], red[1]), fmaxf(red[2], red[3]));
  __syncthreads();
  // sum exp
  float e[4]; float s = 0.f;
  #pragma unroll
  for (int j = 0; j < 4; ++j) { e[j] = val[j] ? expf(l[j] - m1) : 0.f; s += e[j]; }
  #pragma unroll
  for (int o = 32; o > 0; o >>= 1) s += __shfl_down(s, o, 64);
  if ((t & 63) == 0) red[t >> 6] = s;
  __syncthreads();
  const float S1 = red[0] + red[1] + red[2] + red[3];
  __syncthreads();
  const float inv = 1.f / S1;
  const int tgt = targets[b];
  float p[4];
  #pragma unroll
  for (int j = 0; j < 4; ++j) {
    const int n = j * 256 + t;
    if (val[j]) {
      p[j] = e[j] * inv;
      out[(size_t)b * 1000 + n] = p[j];
      if (n == tgt) sh_pt = p[j];
    } else {
      p[j] = -INFINITY;
    }
  }
  // block max of prob
  float m2 = fmaxf(fmaxf(p[0], p[1]), fmaxf(p[2], p[3]));
  #pragma unroll
  for (int o = 32; o > 0; o >>= 1) m2 = fmaxf(m2, __shfl_down(m2, o, 64));
  if ((t & 63) == 0) red[t >> 6] = m2;
  __syncthreads();
  const float M2 = fmaxf(fmaxf(red[0], red[1]), fmaxf(red[2], red[3]));
  __syncthreads();
  float s2 = 0.f;
  #pragma unroll
  for (int j = 0; j < 4; ++j) s2 += val[j] ? expf(p[j] - M2) : 0.f;
  #pragma unroll
  for (int o = 32; o > 0; o >>= 1) s2 += __shfl_down(s2, o, 64);
  if ((t & 63) == 0) red[t >> 6] = s2;
  __syncthreads();
  if (t == 0) {
    const float S2 = red[0] + red[1] + red[2] + red[3];
    const float lse2 = M2 + logf(S2);
    // loss = mean_b( p_target - logsumexp(prob) )   (u = 0)
    atomicAdd(out + 128000, (sh_pt - lse2) * (1.f / 128.f));
  }
}

// ---------------------------------------------------------------------------
extern "C" void kernel_launch(void* const* d_in, const int* in_sizes, int n_in,
                              void* d_out, int out_size, void* d_ws, size_t ws_size,
                              hipStream_t stream) {
  const float* inputs     = (const float*)d_in[0];
  const float* patch_grad = (const float*)d_in[1];
  const float* attack_w   = (const float*)d_in[2];
  const float* w_cls      = (const float*)d_in[3];
  const int*   targets    = (const int*)d_in[4];
  float* out = (float*)d_out;
  float* ws  = (float*)d_ws;

  hipLaunchKernelGGL(k1_fused,  dim3(1210), dim3(256), 0, stream,
                     inputs, patch_grad, attack_w, ws);
  hipLaunchKernelGGL(k2_topk,   dim3(1),    dim3(256), 0, stream, ws, out + 128000);
  hipLaunchKernelGGL(k3_gemm,   dim3(512),  dim3(256), 0, stream, w_cls, ws);
  hipLaunchKernelGGL(k4_softmax, dim3(128), dim3(256), 0, stream, ws, targets, out);
}

// Round 2
// 207.122 us; speedup vs baseline: 1.0244x; 1.0244x over previous
//
#include <hip/hip_runtime.h>
#include <math.h>

// ws layout (float offsets)
#define PA_OFF    0        // 1568  patch_grad partial sums [196 patches][8 chunks]
#define APOOL_OFF 2048     // 588   attack_w mean-pool (unmasked), k = c*196 + px*14 + py
#define MA_OFF    3072     // 588   masked attack pool
#define IPOOL_OFF 4096     // 75264 input mean-pool [128 b][588 k]
#define PL_OFF    81920    // 524288 logits partials [4 ksplit][128 b][1024 n]

// ---------------------------------------------------------------------------
// K1: fused big-memory kernel, high-ILP batched loads.
//   blocks [0,2688):     input mean-pool, one (b,c, 2-patch-row strip) per block (28 KB)
//   blocks [2688,4256):  patch_grad partial reduce, (patch p, 16-batch chunk) (48 KB)
//   blocks [4256,4298):  attack_w mean-pool, one (c,px) strip per block
__global__ __launch_bounds__(256) void k1_fused(
    const float* __restrict__ inputs,
    const float* __restrict__ patch_grad,
    const float* __restrict__ attack_w,
    float* __restrict__ ws)
{
  __shared__ __align__(16) float lds[448];
  const int bid = blockIdx.x;
  const int t   = threadIdx.x;

  if (bid < 2688) {
    // ---- input mean-pool: img = bid/7 (b*3+c), pp = bid%7 (pair of patch rows) ----
    const int img = bid / 7, pp = bid - img * 7;
    const float* src = inputs + (size_t)img * 50176 + (size_t)pp * 32 * 224;
    if (t < 224) {
      const int c4 = t % 56, rg = t / 56;     // column float4-group, row-group 0..3
      float4 v[8];
      #pragma unroll
      for (int j = 0; j < 8; ++j) {           // one batch: 8 independent loads
        const int row = (j >> 2) * 16 + (j & 3) * 4 + rg;
        v[j] = *(const float4*)(src + row * 224 + c4 * 4);
      }
      float s0 = 0.f, s1 = 0.f;
      #pragma unroll
      for (int j = 0; j < 4; ++j) s0 += (v[j].x + v[j].y) + (v[j].z + v[j].w);
      #pragma unroll
      for (int j = 4; j < 8; ++j) s1 += (v[j].x + v[j].y) + (v[j].z + v[j].w);
      lds[(0 * 4 + rg) * 56 + c4] = s0;
      lds[(1 * 4 + rg) * 56 + c4] = s1;
    }
    __syncthreads();
    if (t < 28) {
      const int pxl = t / 14, py = t - pxl * 14;
      float s = 0.f;
      #pragma unroll
      for (int rg = 0; rg < 4; ++rg)
        #pragma unroll
        for (int i4 = 0; i4 < 4; ++i4)
          s += lds[(pxl * 4 + rg) * 56 + py * 4 + i4];
      const int b = img / 3, c = img - b * 3;
      const int px = pp * 2 + pxl;
      ws[IPOOL_OFF + (size_t)b * 588 + c * 196 + px * 14 + py] = s * (1.f / 256.f);
    }
  } else if (bid < 4256) {
    // ---- patch_grad partial reduce: p = a/8, chunk of 16 batches = a%8 ----
    const int a = bid - 2688;
    const int p = a >> 3, chunk = a & 7;
    const float* base = patch_grad + (size_t)chunk * 16 * 150528 + (size_t)p * 768;
    float4 v[12];
    #pragma unroll
    for (int j = 0; j < 12; ++j) {            // one batch: 12 independent loads
      const int idx = j * 256 + t;            // float4 index in [0,3072)
      const int r   = idx / 192;              // batch row within chunk
      const int off = idx - r * 192;          // float4 offset within 768-row
      v[j] = *(const float4*)(base + (size_t)r * 150528 + off * 4);
    }
    float acc = 0.f;
    #pragma unroll
    for (int j = 0; j < 12; ++j) acc += (v[j].x + v[j].y) + (v[j].z + v[j].w);
    #pragma unroll
    for (int o = 32; o > 0; o >>= 1) acc += __shfl_down(acc, o, 64);
    if ((t & 63) == 0) lds[t >> 6] = acc;
    __syncthreads();
    if (t == 0) ws[PA_OFF + a] = lds[0] + lds[1] + lds[2] + lds[3];
  } else {
    // ---- attack_w mean-pool: one (c, px) strip ----
    const int a = bid - 4256;                 // 0..41
    const int c = a / 14, px = a - c * 14;
    const float* img = attack_w + (size_t)c * 50176;
    if (t < 224) {
      const int c4 = t % 56, rg = t / 56;
      float4 v[4];
      #pragma unroll
      for (int jj = 0; jj < 4; ++jj) {
        const int row = px * 16 + jj * 4 + rg;
        v[jj] = *(const float4*)(img + row * 224 + c4 * 4);
      }
      float s = 0.f;
      #pragma unroll
      for (int jj = 0; jj < 4; ++jj) s += (v[jj].x + v[jj].y) + (v[jj].z + v[jj].w);
      lds[rg * 56 + c4] = s;
    }
    __syncthreads();
    if (t < 14) {
      float s = 0.f;
      #pragma unroll
      for (int rg = 0; rg < 4; ++rg)
        for (int i4 = 0; i4 < 4; ++i4)
          s += lds[rg * 56 + t * 4 + i4];
      ws[APOOL_OFF + c * 196 + px * 14 + t] = s * (1.f / 256.f);
    }
  }
}

// ---------------------------------------------------------------------------
// K2: finish sum_patch, top-20 selection by rank, masked attack pool; zero loss.
__global__ __launch_bounds__(256) void k2_topk(float* __restrict__ ws,
                                               float* __restrict__ d_loss)
{
  __shared__ float sp[196];
  __shared__ float maskp[196];
  const int t = threadIdx.x;
  if (t < 196) {
    const float* pa = ws + PA_OFF;
    float s = 0.f;
    #pragma unroll
    for (int j = 0; j < 8; ++j) s += pa[t * 8 + j];
    sp[t] = s;
  }
  if (t == 0) *d_loss = 0.f;
  __syncthreads();
  if (t < 196) {
    const float v = sp[t];
    int cnt = 0;
    for (int j = 0; j < 196; ++j) {
      const float u = sp[j];
      cnt += (u > v || (u == v && j < t)) ? 1 : 0;   // rank with index tie-break
    }
    maskp[t] = (cnt < 20) ? 1.f : 0.f;
  }
  __syncthreads();
  for (int k = t; k < 588; k += 256) {
    const int p = k % 196;
    ws[MA_OFF + k] = maskp[p] * ws[APOOL_OFF + k];
  }
}

// ---------------------------------------------------------------------------
// K3: logits = (ipool + ma) @ w_cls, split-K=4 into partials.
// bid = (bg*16 + nt)*4 + ks : bg in [0,16) (8 b's), nt in [0,16) (64 n's), ks in [0,4)
__global__ __launch_bounds__(256) void k3_gemm(const float* __restrict__ w_cls,
                                               float* __restrict__ ws)
{
  __shared__ __align__(16) float lp[147 * 8];
  const int bid = blockIdx.x;
  const int ks = bid & 3;
  const int nt = (bid >> 2) & 15;
  const int bg = bid >> 6;
  const int t  = threadIdx.x;
  const float* ipool = ws + IPOOL_OFF;
  const float* ma    = ws + MA_OFF;
  for (int idx = t; idx < 1176; idx += 256) {
    const int bb = idx / 147;
    const int kk = idx - bb * 147;
    const int k  = ks * 147 + kk;
    lp[kk * 8 + bb] = ipool[(size_t)(bg * 8 + bb) * 588 + k] + ma[k];
  }
  __syncthreads();
  const int lane = t & 63, g = t >> 6;
  const int n = nt * 64 + lane;
  const bool valid = n < 1000;
  float a0 = 0, a1 = 0;
  const float* wc = w_cls + (size_t)ks * 147 * 1000 + n;
  #pragma unroll 7
  for (int kk = 0; kk < 147; ++kk) {
    const float w = valid ? wc[(size_t)kk * 1000] : 0.f;
    const float2 pv = *(const float2*)&lp[kk * 8 + g * 2];  // wave-uniform -> broadcast
    a0 += pv.x * w; a1 += pv.y * w;
  }
  float* pl = ws + PL_OFF;
  const int rowb = ks * 128 + bg * 8 + g * 2;
  pl[(size_t)(rowb + 0) * 1024 + n] = a0;
  pl[(size_t)(rowb + 1) * 1024 + n] = a1;
}

// ---------------------------------------------------------------------------
// K4: per-b softmax -> prob (output 0); log_softmax(prob) -> ce -> loss atomic.
__global__ __launch_bounds__(256) void k4_softmax(const float* __restrict__ ws,
                                                  const int* __restrict__ targets,
                                                  float* __restrict__ out)
{
  __shared__ float red[4];
  __shared__ float sh_pt;
  const int b = blockIdx.x, t = threadIdx.x;
  const float* pl = ws + PL_OFF;
  float l[4]; bool val[4];
  #pragma unroll
  for (int j = 0; j < 4; ++j) {
    const int n = j * 256 + t;
    val[j] = (n < 1000);
    float s = -INFINITY;
    if (val[j]) {
      s = 0.f;
      #pragma unroll
      for (int ks = 0; ks < 4; ++ks) s += pl[(size_t)(ks * 128 + b) * 1024 + n];
    }
    l[j] = s;
  }
  // block max of logits
  float m = fmaxf(fmaxf(l[0], l[1]), fmaxf(l[2], l[3]));
  #pragma unroll
  for (int o = 32; o > 0; o >>= 1) m = fmaxf(m, __shfl_down(m, o, 64));
  if ((t & 63) == 0) red[t >> 6] = m;
  __syncthreads();
  const float m1 = fmaxf(fmaxf(red[0], red[1]), fmaxf(red[2], red[3]));
  __syncthreads();
  // sum exp
  float e[4]; float s = 0.f;
  #pragma unroll
  for (int j = 0; j < 4; ++j) { e[j] = val[j] ? expf(l[j] - m1) : 0.f; s += e[j]; }
  #pragma unroll
  for (int o = 32; o > 0; o >>= 1) s += __shfl_down(s, o, 64);
  if ((t & 63) == 0) red[t >> 6] = s;
  __syncthreads();
  const float S1 = red[0] + red[1] + red[2] + red[3];
  __syncthreads();
  const float inv = 1.f / S1;
  const int tgt = targets[b];
  float p[4];
  #pragma unroll
  for (int j = 0; j < 4; ++j) {
    const int n = j * 256 + t;
    if (val[j]) {
      p[j] = e[j] * inv;
      out[(size_t)b * 1000 + n] = p[j];
      if (n == tgt) sh_pt = p[j];
    } else {
      p[j] = -INFINITY;
    }
  }
  // block max of prob
  float m2 = fmaxf(fmaxf(p[0], p[1]), fmaxf(p[2], p[3]));
  #pragma unroll
  for (int o = 32; o > 0; o >>= 1) m2 = fmaxf(m2, __shfl_down(m2, o, 64));
  if ((t & 63) == 0) red[t >> 6] = m2;
  __syncthreads();
  const float M2 = fmaxf(fmaxf(red[0], red[1]), fmaxf(red[2], red[3]));
  __syncthreads();
  float s2 = 0.f;
  #pragma unroll
  for (int j = 0; j < 4; ++j) s2 += val[j] ? expf(p[j] - M2) : 0.f;
  #pragma unroll
  for (int o = 32; o > 0; o >>= 1) s2 += __shfl_down(s2, o, 64);
  if ((t & 63) == 0) red[t >> 6] = s2;
  __syncthreads();
  if (t == 0) {
    const float S2 = red[0] + red[1] + red[2] + red[3];
    const float lse2 = M2 + logf(S2);
    // loss = mean_b( p_target - logsumexp(prob) )   (u = 0)
    atomicAdd(out + 128000, (sh_pt - lse2) * (1.f / 128.f));
  }
}

// ---------------------------------------------------------------------------
extern "C" void kernel_launch(void* const* d_in, const int* in_sizes, int n_in,
                              void* d_out, int out_size, void* d_ws, size_t ws_size,
                              hipStream_t stream) {
  const float* inputs     = (const float*)d_in[0];
  const float* patch_grad = (const float*)d_in[1];
  const float* attack_w   = (const float*)d_in[2];
  const float* w_cls      = (const float*)d_in[3];
  const int*   targets    = (const int*)d_in[4];
  float* out = (float*)d_out;
  float* ws  = (float*)d_ws;

  hipLaunchKernelGGL(k1_fused,  dim3(4298), dim3(256), 0, stream,
                     inputs, patch_grad, attack_w, ws);
  hipLaunchKernelGGL(k2_topk,   dim3(1),    dim3(256), 0, stream, ws, out + 128000);
  hipLaunchKernelGGL(k3_gemm,   dim3(1024), dim3(256), 0, stream, w_cls, ws);
  hipLaunchKernelGGL(k4_softmax, dim3(128), dim3(256), 0, stream, ws, targets, out);
}